// Round 1
// baseline (276.677 us; speedup 1.0000x reference)
//
#include <hip/hip_runtime.h>
#include <hip/hip_bf16.h>
#include <math.h>

#define Bn 8192
#define Dn 256
#define Pn 4096

using f16x8 = _Float16 __attribute__((ext_vector_type(8)));
using f16x4 = _Float16 __attribute__((ext_vector_type(4)));
using f32x16 = float __attribute__((ext_vector_type(16)));

// ---------------- normalize rows (fp32 -> f16), one wave per row ----------------
__global__ void norm_rows_kernel(const float* __restrict__ in, _Float16* __restrict__ out) {
    int row  = blockIdx.x * 4 + (threadIdx.x >> 6);
    int lane = threadIdx.x & 63;
    const float4 v = reinterpret_cast<const float4*>(in + (size_t)row * Dn)[lane];
    float ss = v.x * v.x + v.y * v.y + v.z * v.z + v.w * v.w;
#pragma unroll
    for (int m = 1; m <= 32; m <<= 1) ss += __shfl_xor(ss, m);
    float scale = 1.0f / fmaxf(sqrtf(ss), 1e-12f);
    f16x4 o;
    o[0] = (_Float16)(v.x * scale);
    o[1] = (_Float16)(v.y * scale);
    o[2] = (_Float16)(v.z * scale);
    o[3] = (_Float16)(v.w * scale);
    reinterpret_cast<f16x4*>(out + (size_t)row * Dn)[lane] = o;
}

// ---------------- GEMM + exp-sum: s[row] = sum_p exp(sim[row][p] - 2) ----------------
// Per wave: 32 rows, A frags fully in registers (K=256). B frags streamed from L2.
// grid = (8192/128, 4096/512), block = 256 (4 waves)
__global__ __launch_bounds__(256, 2)
void gemm_expsum_kernel(const _Float16* __restrict__ embn, const _Float16* __restrict__ pron,
                        float* __restrict__ s_glob) {
    const int w    = threadIdx.x >> 6;
    const int lane = threadIdx.x & 63;
    const int lo   = lane & 31;
    const int hi   = lane >> 5;
    const int rbase = blockIdx.x * 128 + w * 32;
    const int cbase = blockIdx.y * 512;

    // A fragments: lane lo -> row rbase+lo, elems k = kk*16 + hi*8 + j
    const _Float16* ap = embn + (size_t)(rbase + lo) * Dn + hi * 8;
    f16x8 a[16];
#pragma unroll
    for (int kk = 0; kk < 16; ++kk)
        a[kk] = *reinterpret_cast<const f16x8*>(ap + kk * 16);

    float s[16];
#pragma unroll
    for (int r = 0; r < 16; ++r) s[r] = 0.0f;

    const _Float16* bp0 = pron + (size_t)(cbase + lo) * Dn + hi * 8;
    constexpr float K1 = 2.0f * 1.4426950408889634f;  // (1/TEMP) * log2(e)

    for (int ct = 0; ct < 16; ++ct) {
        const _Float16* bp = bp0 + (size_t)ct * 32 * Dn;
        f32x16 acc;
#pragma unroll
        for (int r = 0; r < 16; ++r) acc[r] = 0.0f;
#pragma unroll
        for (int kk = 0; kk < 16; ++kk) {
            f16x8 b = *reinterpret_cast<const f16x8*>(bp + kk * 16);
            acc = __builtin_amdgcn_mfma_f32_32x32x16_f16(a[kk], b, acc, 0, 0, 0);
        }
        // sim = acc * 2; add exp(sim - 2) = exp2(acc*K1 - K1)
#pragma unroll
        for (int r = 0; r < 16; ++r)
            s[r] += exp2f(acc[r] * K1 - K1);
    }

    // reduce across the 32 lanes holding the same row (cols), then atomicAdd per row
#pragma unroll
    for (int r = 0; r < 16; ++r) {
        float v = s[r];
        v += __shfl_xor(v, 1);
        v += __shfl_xor(v, 2);
        v += __shfl_xor(v, 4);
        v += __shfl_xor(v, 8);
        v += __shfl_xor(v, 16);
        if (lo == 0) {
            int row = rbase + (r & 3) + 8 * (r >> 2) + 4 * hi;
            atomicAdd(&s_glob[row], v);
        }
    }
}

// ---------------- loss finalize: pos dot + lse - mean ----------------
__global__ void loss_kernel(const _Float16* __restrict__ embn, const _Float16* __restrict__ pron,
                            const int* __restrict__ cid, const float* __restrict__ s_glob,
                            float* __restrict__ loss) {
    int row  = blockIdx.x * 4 + (threadIdx.x >> 6);
    int lane = threadIdx.x & 63;
    int c = cid[row];
    f16x4 e = reinterpret_cast<const f16x4*>(embn + (size_t)row * Dn)[lane];
    f16x4 p = reinterpret_cast<const f16x4*>(pron + (size_t)c * Dn)[lane];
    float d = 0.0f;
#pragma unroll
    for (int j = 0; j < 4; ++j) d += (float)e[j] * (float)p[j];
#pragma unroll
    for (int m = 1; m <= 32; m <<= 1) d += __shfl_xor(d, m);
    if (lane == 0) {
        float pos  = d * 2.0f;
        float sneg = s_glob[row] - __expf(pos - 2.0f);   // remove positive column
        float lse  = __logf(sneg) + 2.0f;
        atomicAdd(loss, (lse - pos) * (1.0f / (float)Bn));
    }
}

// ---------------- EMA update: ranks via chunk histograms, then scatter ----------------
__global__ void hist_kernel(const int* __restrict__ cid, int* __restrict__ hist) {
    __shared__ int h[Pn];
    for (int c = threadIdx.x; c < Pn; c += 256) h[c] = 0;
    __syncthreads();
    int i = blockIdx.x * 256 + threadIdx.x;
    atomicAdd(&h[cid[i]], 1);
    __syncthreads();
    for (int c = threadIdx.x; c < Pn; c += 256)
        hist[blockIdx.x * Pn + c] = h[c];
}

__global__ void rank_kernel(const int* __restrict__ cid, const int* __restrict__ hist,
                            int* __restrict__ rank) {
    __shared__ int ids[256];
    int t = threadIdx.x;
    int i = blockIdx.x * 256 + t;
    ids[t] = cid[i];
    __syncthreads();
    int my = ids[t];
    int r = 0;
    for (int ch = 0; ch < (int)blockIdx.x; ++ch) r += hist[ch * Pn + my];
    for (int j = 0; j < t; ++j) r += (ids[j] == my) ? 1 : 0;
    rank[i] = r;
}

__global__ void counts_kernel(const int* __restrict__ hist, int* __restrict__ counts) {
    int c = blockIdx.x * 256 + threadIdx.x;
    int s = 0;
#pragma unroll
    for (int ch = 0; ch < 32; ++ch) s += hist[ch * Pn + c];
    counts[c] = s;
}

__global__ void init_out_kernel(const float* __restrict__ protos, const int* __restrict__ counts,
                                float* __restrict__ outp) {
    int idx = blockIdx.x * 256 + threadIdx.x;
    int c   = idx >> 8;
    outp[idx] = __powf(0.9f, (float)counts[c]) * protos[idx];
}

__global__ void scatter_kernel(const float* __restrict__ emb, const int* __restrict__ cid,
                               const int* __restrict__ rank, const int* __restrict__ counts,
                               float* __restrict__ outp) {
    int i = blockIdx.x;
    int d = threadIdx.x;
    int c = cid[i];
    float wgt = 0.1f * __powf(0.9f, (float)(counts[c] - 1 - rank[i]));
    atomicAdd(&outp[(size_t)c * Dn + d], wgt * emb[(size_t)i * Dn + d]);
}

extern "C" void kernel_launch(void* const* d_in, const int* in_sizes, int n_in,
                              void* d_out, int out_size, void* d_ws, size_t ws_size,
                              hipStream_t stream) {
    const float* emb    = (const float*)d_in[0];
    const float* protos = (const float*)d_in[1];
    const int*   cid    = (const int*)d_in[2];
    float* out = (float*)d_out;

    char* ws = (char*)d_ws;
    _Float16* embn = (_Float16*)ws;                                  // 4 MB
    _Float16* pron = (_Float16*)(ws + ((size_t)4 << 20));            // 2 MB
    float* s_glob  = (float*)(ws + ((size_t)6 << 20));               // 32 KB
    int*   counts  = (int*)(ws + ((size_t)6 << 20) + 32768);         // 16 KB
    int*   rank    = (int*)(ws + ((size_t)6 << 20) + 49152);         // 32 KB
    int*   hist    = (int*)(ws + ((size_t)6 << 20) + 81920);         // 512 KB

    hipMemsetAsync(out, 0, sizeof(float), stream);        // loss accumulator
    hipMemsetAsync(s_glob, 0, Bn * sizeof(float), stream);

    norm_rows_kernel<<<Bn / 4, 256, 0, stream>>>(emb, embn);
    norm_rows_kernel<<<Pn / 4, 256, 0, stream>>>(protos, pron);

    gemm_expsum_kernel<<<dim3(Bn / 128, Pn / 512), 256, 0, stream>>>(embn, pron, s_glob);
    loss_kernel<<<Bn / 4, 256, 0, stream>>>(embn, pron, cid, s_glob, out);

    hist_kernel<<<Bn / 256, 256, 0, stream>>>(cid, hist);
    rank_kernel<<<Bn / 256, 256, 0, stream>>>(cid, hist, rank);
    counts_kernel<<<Pn / 256, 256, 0, stream>>>(hist, counts);
    init_out_kernel<<<(Pn * Dn) / 256, 256, 0, stream>>>(protos, counts, out + 1);
    scatter_kernel<<<Bn, 256, 0, stream>>>(emb, cid, rank, counts, out + 1);
}

// Round 2
// 172.070 us; speedup vs baseline: 1.6079x; 1.6079x over previous
//
#include <hip/hip_runtime.h>
#include <hip/hip_bf16.h>
#include <math.h>

#define Bn 8192
#define Dn 256
#define Pn 4096

using f16x8 = _Float16 __attribute__((ext_vector_type(8)));
using f16x4 = _Float16 __attribute__((ext_vector_type(4)));
using f32x16 = float __attribute__((ext_vector_type(16)));

// ---------------- normalize rows (fp32 -> f16), one wave per row ----------------
__global__ void norm_rows_kernel(const float* __restrict__ in, _Float16* __restrict__ out) {
    int row  = blockIdx.x * 4 + (threadIdx.x >> 6);
    int lane = threadIdx.x & 63;
    const float4 v = reinterpret_cast<const float4*>(in + (size_t)row * Dn)[lane];
    float ss = v.x * v.x + v.y * v.y + v.z * v.z + v.w * v.w;
#pragma unroll
    for (int m = 1; m <= 32; m <<= 1) ss += __shfl_xor(ss, m);
    float scale = 1.0f / fmaxf(sqrtf(ss), 1e-12f);
    f16x4 o;
    o[0] = (_Float16)(v.x * scale);
    o[1] = (_Float16)(v.y * scale);
    o[2] = (_Float16)(v.z * scale);
    o[3] = (_Float16)(v.w * scale);
    reinterpret_cast<f16x4*>(out + (size_t)row * Dn)[lane] = o;
}

// ---------------- GEMM + exp-sum: s[row] = sum_p exp(sim[row][p] - 2) ----------------
// Per wave: 32 rows, A frags fully in registers (K=256). B frags streamed from L2.
// grid = (8192/128, 4096/512), block = 256 (4 waves)
__global__ __launch_bounds__(256, 2)
void gemm_expsum_kernel(const _Float16* __restrict__ embn, const _Float16* __restrict__ pron,
                        float* __restrict__ s_glob) {
    const int w    = threadIdx.x >> 6;
    const int lane = threadIdx.x & 63;
    const int lo   = lane & 31;
    const int hi   = lane >> 5;
    const int rbase = blockIdx.x * 128 + w * 32;
    const int cbase = blockIdx.y * 512;

    // A fragments: lane lo -> row rbase+lo, elems k = kk*16 + hi*8 + j
    const _Float16* ap = embn + (size_t)(rbase + lo) * Dn + hi * 8;
    f16x8 a[16];
#pragma unroll
    for (int kk = 0; kk < 16; ++kk)
        a[kk] = *reinterpret_cast<const f16x8*>(ap + kk * 16);

    float s[16];
#pragma unroll
    for (int r = 0; r < 16; ++r) s[r] = 0.0f;

    const _Float16* bp0 = pron + (size_t)(cbase + lo) * Dn + hi * 8;
    constexpr float K1 = 2.0f * 1.4426950408889634f;  // (1/TEMP) * log2(e)

    for (int ct = 0; ct < 16; ++ct) {
        const _Float16* bp = bp0 + (size_t)ct * 32 * Dn;
        f32x16 acc;
#pragma unroll
        for (int r = 0; r < 16; ++r) acc[r] = 0.0f;
#pragma unroll
        for (int kk = 0; kk < 16; ++kk) {
            f16x8 b = *reinterpret_cast<const f16x8*>(bp + kk * 16);
            acc = __builtin_amdgcn_mfma_f32_32x32x16_f16(a[kk], b, acc, 0, 0, 0);
        }
        // sim = acc * 2; add exp(sim - 2) = exp2(acc*K1 - K1)
#pragma unroll
        for (int r = 0; r < 16; ++r)
            s[r] += exp2f(acc[r] * K1 - K1);
    }

    // reduce across the 32 lanes holding the same row (cols), then atomicAdd per row
#pragma unroll
    for (int r = 0; r < 16; ++r) {
        float v = s[r];
        v += __shfl_xor(v, 1);
        v += __shfl_xor(v, 2);
        v += __shfl_xor(v, 4);
        v += __shfl_xor(v, 8);
        v += __shfl_xor(v, 16);
        if (lo == 0) {
            int row = rbase + (r & 3) + 8 * (r >> 2) + 4 * hi;
            atomicAdd(&s_glob[row], v);
        }
    }
}

// ---------------- loss terms: per-row (lse - pos), NO contended atomic ----------------
__global__ void loss_kernel(const _Float16* __restrict__ embn, const _Float16* __restrict__ pron,
                            const int* __restrict__ cid, const float* __restrict__ s_glob,
                            float* __restrict__ terms) {
    int row  = blockIdx.x * 4 + (threadIdx.x >> 6);
    int lane = threadIdx.x & 63;
    int c = cid[row];
    f16x4 e = reinterpret_cast<const f16x4*>(embn + (size_t)row * Dn)[lane];
    f16x4 p = reinterpret_cast<const f16x4*>(pron + (size_t)c * Dn)[lane];
    float d = 0.0f;
#pragma unroll
    for (int j = 0; j < 4; ++j) d += (float)e[j] * (float)p[j];
#pragma unroll
    for (int m = 1; m <= 32; m <<= 1) d += __shfl_xor(d, m);
    if (lane == 0) {
        float pos  = d * 2.0f;
        float sneg = s_glob[row] - __expf(pos - 2.0f);   // remove positive column
        float lse  = __logf(sneg) + 2.0f;
        terms[row] = lse - pos;
    }
}

// ---------------- single-block tree reduce of 8192 terms -> mean ----------------
__global__ void reduce_loss_kernel(const float* __restrict__ terms, float* __restrict__ loss) {
    int t = threadIdx.x;
    const float4* T = reinterpret_cast<const float4*>(terms);
    float s = 0.0f;
#pragma unroll
    for (int i = 0; i < Bn / 4 / 256; ++i) {
        float4 v = T[i * 256 + t];
        s += v.x + v.y + v.z + v.w;
    }
#pragma unroll
    for (int m = 1; m <= 32; m <<= 1) s += __shfl_xor(s, m);
    __shared__ float wsum[4];
    if ((t & 63) == 0) wsum[t >> 6] = s;
    __syncthreads();
    if (t == 0) loss[0] = (wsum[0] + wsum[1] + wsum[2] + wsum[3]) * (1.0f / (float)Bn);
}

// ---------------- EMA update: ranks via chunk histograms, then scatter ----------------
__global__ void hist_kernel(const int* __restrict__ cid, int* __restrict__ hist) {
    __shared__ int h[Pn];
    for (int c = threadIdx.x; c < Pn; c += 256) h[c] = 0;
    __syncthreads();
    int i = blockIdx.x * 256 + threadIdx.x;
    atomicAdd(&h[cid[i]], 1);
    __syncthreads();
    for (int c = threadIdx.x; c < Pn; c += 256)
        hist[blockIdx.x * Pn + c] = h[c];
}

__global__ void rank_kernel(const int* __restrict__ cid, const int* __restrict__ hist,
                            int* __restrict__ rank) {
    __shared__ int ids[256];
    int t = threadIdx.x;
    int i = blockIdx.x * 256 + t;
    ids[t] = cid[i];
    __syncthreads();
    int my = ids[t];
    int r = 0;
    for (int ch = 0; ch < (int)blockIdx.x; ++ch) r += hist[ch * Pn + my];
    for (int j = 0; j < t; ++j) r += (ids[j] == my) ? 1 : 0;
    rank[i] = r;
}

__global__ void counts_kernel(const int* __restrict__ hist, int* __restrict__ counts) {
    int c = blockIdx.x * 256 + threadIdx.x;
    int s = 0;
#pragma unroll
    for (int ch = 0; ch < 32; ++ch) s += hist[ch * Pn + c];
    counts[c] = s;
}

__global__ void init_out_kernel(const float* __restrict__ protos, const int* __restrict__ counts,
                                float* __restrict__ outp) {
    int idx = blockIdx.x * 256 + threadIdx.x;
    int c   = idx >> 8;
    outp[idx] = __powf(0.9f, (float)counts[c]) * protos[idx];
}

__global__ void scatter_kernel(const float* __restrict__ emb, const int* __restrict__ cid,
                               const int* __restrict__ rank, const int* __restrict__ counts,
                               float* __restrict__ outp) {
    int i = blockIdx.x;
    int d = threadIdx.x;
    int c = cid[i];
    float wgt = 0.1f * __powf(0.9f, (float)(counts[c] - 1 - rank[i]));
    atomicAdd(&outp[(size_t)c * Dn + d], wgt * emb[(size_t)i * Dn + d]);
}

extern "C" void kernel_launch(void* const* d_in, const int* in_sizes, int n_in,
                              void* d_out, int out_size, void* d_ws, size_t ws_size,
                              hipStream_t stream) {
    const float* emb    = (const float*)d_in[0];
    const float* protos = (const float*)d_in[1];
    const int*   cid    = (const int*)d_in[2];
    float* out = (float*)d_out;

    char* ws = (char*)d_ws;
    _Float16* embn = (_Float16*)ws;                                  // 4 MB
    _Float16* pron = (_Float16*)(ws + ((size_t)4 << 20));            // 2 MB
    float* s_glob  = (float*)(ws + ((size_t)6 << 20));               // 32 KB
    int*   counts  = (int*)(ws + ((size_t)6 << 20) + 32768);         // 16 KB
    int*   rank    = (int*)(ws + ((size_t)6 << 20) + 49152);         // 32 KB
    float* terms   = (float*)(ws + ((size_t)6 << 20) + 81920);       // 32 KB
    int*   hist    = (int*)(ws + ((size_t)6 << 20) + 114688);        // 512 KB

    hipMemsetAsync(s_glob, 0, Bn * sizeof(float), stream);

    norm_rows_kernel<<<Bn / 4, 256, 0, stream>>>(emb, embn);
    norm_rows_kernel<<<Pn / 4, 256, 0, stream>>>(protos, pron);

    gemm_expsum_kernel<<<dim3(Bn / 128, Pn / 512), 256, 0, stream>>>(embn, pron, s_glob);
    loss_kernel<<<Bn / 4, 256, 0, stream>>>(embn, pron, cid, s_glob, terms);
    reduce_loss_kernel<<<1, 256, 0, stream>>>(terms, out);

    hist_kernel<<<Bn / 256, 256, 0, stream>>>(cid, hist);
    rank_kernel<<<Bn / 256, 256, 0, stream>>>(cid, hist, rank);
    counts_kernel<<<Pn / 256, 256, 0, stream>>>(hist, counts);
    init_out_kernel<<<(Pn * Dn) / 256, 256, 0, stream>>>(protos, counts, out + 1);
    scatter_kernel<<<Bn, 256, 0, stream>>>(emb, cid, rank, counts, out + 1);
}

// Round 3
// 169.828 us; speedup vs baseline: 1.6292x; 1.0132x over previous
//
#include <hip/hip_runtime.h>
#include <hip/hip_bf16.h>
#include <math.h>

#define Bn 8192
#define Dn 256
#define Pn 4096

using f16x8 = _Float16 __attribute__((ext_vector_type(8)));
using f16x4 = _Float16 __attribute__((ext_vector_type(4)));
using f32x16 = float __attribute__((ext_vector_type(16)));

// ---------------- normalize rows (fp32 -> f16), one wave per row ----------------
__global__ void norm_rows_kernel(const float* __restrict__ in, _Float16* __restrict__ out) {
    int row  = blockIdx.x * 4 + (threadIdx.x >> 6);
    int lane = threadIdx.x & 63;
    const float4 v = reinterpret_cast<const float4*>(in + (size_t)row * Dn)[lane];
    float ss = v.x * v.x + v.y * v.y + v.z * v.z + v.w * v.w;
#pragma unroll
    for (int m = 1; m <= 32; m <<= 1) ss += __shfl_xor(ss, m);
    float scale = 1.0f / fmaxf(sqrtf(ss), 1e-12f);
    f16x4 o;
    o[0] = (_Float16)(v.x * scale);
    o[1] = (_Float16)(v.y * scale);
    o[2] = (_Float16)(v.z * scale);
    o[3] = (_Float16)(v.w * scale);
    reinterpret_cast<f16x4*>(out + (size_t)row * Dn)[lane] = o;
}

// ---------------- GEMM + exp-sum: s[row] += sum_p exp(sim-2) ----------------
// Block: 128 rows x 256 cols, 4 waves (32 rows each). B staged in LDS via
// global_load_lds, double-buffered 32-col sub-chunks, XOR-swizzled vs bank
// conflicts (linear LDS dest + inverse-swizzled global source, rule 21).
// grid = (8192/128, 4096/256) = (64,16) -> 4 blocks/CU.
__global__ __launch_bounds__(256, 4)
void gemm_expsum_kernel(const _Float16* __restrict__ embn, const _Float16* __restrict__ pron,
                        float* __restrict__ s_glob) {
    __shared__ _Float16 Bs[2][32 * Dn];   // 2 x 16 KB
    const int w    = threadIdx.x >> 6;
    const int lane = threadIdx.x & 63;
    const int lo   = lane & 31;
    const int hi   = lane >> 5;
    const int rbase = blockIdx.x * 128 + w * 32;
    const int cbase = blockIdx.y * 256;

    // A fragments: lane lo -> row rbase+lo, elems k = kk*16 + hi*8 + j
    const _Float16* ap = embn + (size_t)(rbase + lo) * Dn + hi * 8;
    f16x8 a[16];
#pragma unroll
    for (int kk = 0; kk < 16; ++kk)
        a[kk] = *reinterpret_cast<const f16x8*>(ap + kk * 16);

    float s[16];
#pragma unroll
    for (int r = 0; r < 16; ++r) s[r] = 0.0f;

    constexpr float K1 = 2.0f * 1.4426950408889634f;  // (1/TEMP) * log2(e)

    // stage sub-chunk `sub` (32 cols x 256 k = 16 KB) into buf.
    // LDS dest linear; global source inverse-swizzled: byte ^= (col&7)<<4.
    auto stage = [&](int sub, _Float16* buf) {
#pragma unroll
        for (int i = 0; i < 4; ++i) {
            int gran  = (i * 4 + w) * 64 + lane;      // 0..1023 (16B granules)
            int col   = gran >> 5;                    // 32 granules (512B) per col
            int gi    = gran & 31;
            int inner = (gi * 16) ^ ((col & 7) << 4);
            const char* g = (const char*)(pron + (size_t)(cbase + sub * 32 + col) * Dn) + inner;
            char* l = (char*)buf + ((i * 4 + w) << 10);   // wave-uniform base
            __builtin_amdgcn_global_load_lds(
                (const __attribute__((address_space(1))) unsigned int*)g,
                (__attribute__((address_space(3))) unsigned int*)l, 16, 0, 0);
        }
    };

    stage(0, Bs[0]);
    __syncthreads();

    for (int sub = 0; sub < 8; ++sub) {
        const _Float16* cur = Bs[sub & 1];
        if (sub < 7) stage(sub + 1, Bs[(sub + 1) & 1]);   // async prefetch

        f32x16 acc;
#pragma unroll
        for (int r = 0; r < 16; ++r) acc[r] = 0.0f;
#pragma unroll
        for (int kk = 0; kk < 16; ++kk) {
            int addr = (lo << 9) + (kk << 5) + (hi << 4);
            addr ^= (lo & 7) << 4;                         // read-side swizzle
            f16x8 b = *reinterpret_cast<const f16x8*>((const char*)cur + addr);
            acc = __builtin_amdgcn_mfma_f32_32x32x16_f16(a[kk], b, acc, 0, 0, 0);
        }
#pragma unroll
        for (int r = 0; r < 16; ++r)
            s[r] += exp2f(acc[r] * K1 - K1);

        __syncthreads();   // drains vmcnt (prefetch landed) + read-done for next overwrite
    }

    // reduce across the 32 lanes holding the same row, then atomicAdd per row
#pragma unroll
    for (int r = 0; r < 16; ++r) {
        float v = s[r];
        v += __shfl_xor(v, 1);
        v += __shfl_xor(v, 2);
        v += __shfl_xor(v, 4);
        v += __shfl_xor(v, 8);
        v += __shfl_xor(v, 16);
        if (lo == 0) {
            int row = rbase + (r & 3) + 8 * (r >> 2) + 4 * hi;
            atomicAdd(&s_glob[row], v);
        }
    }
}

// ---------------- loss terms: per-row (lse - pos) ----------------
__global__ void loss_kernel(const _Float16* __restrict__ embn, const _Float16* __restrict__ pron,
                            const int* __restrict__ cid, const float* __restrict__ s_glob,
                            float* __restrict__ terms) {
    int row  = blockIdx.x * 4 + (threadIdx.x >> 6);
    int lane = threadIdx.x & 63;
    int c = cid[row];
    f16x4 e = reinterpret_cast<const f16x4*>(embn + (size_t)row * Dn)[lane];
    f16x4 p = reinterpret_cast<const f16x4*>(pron + (size_t)c * Dn)[lane];
    float d = 0.0f;
#pragma unroll
    for (int j = 0; j < 4; ++j) d += (float)e[j] * (float)p[j];
#pragma unroll
    for (int m = 1; m <= 32; m <<= 1) d += __shfl_xor(d, m);
    if (lane == 0) {
        float pos  = d * 2.0f;
        float sneg = s_glob[row] - __expf(pos - 2.0f);   // remove positive column
        float lse  = __logf(sneg) + 2.0f;
        terms[row] = lse - pos;
    }
}

// ---------------- single-block tree reduce of 8192 terms -> mean ----------------
__global__ void reduce_loss_kernel(const float* __restrict__ terms, float* __restrict__ loss) {
    int t = threadIdx.x;
    const float4* T = reinterpret_cast<const float4*>(terms);
    float s = 0.0f;
#pragma unroll
    for (int i = 0; i < Bn / 4 / 256; ++i) {
        float4 v = T[i * 256 + t];
        s += v.x + v.y + v.z + v.w;
    }
#pragma unroll
    for (int m = 1; m <= 32; m <<= 1) s += __shfl_xor(s, m);
    __shared__ float wsum[4];
    if ((t & 63) == 0) wsum[t >> 6] = s;
    __syncthreads();
    if (t == 0) loss[0] = (wsum[0] + wsum[1] + wsum[2] + wsum[3]) * (1.0f / (float)Bn);
}

// ---------------- EMA path: hist -> counts+prefix -> rank -> offsets -> CSR -> gather ----------------
__global__ void hist_kernel(const int* __restrict__ cid, int* __restrict__ hist) {
    __shared__ int h[Pn];
    for (int c = threadIdx.x; c < Pn; c += 256) h[c] = 0;
    __syncthreads();
    int i = blockIdx.x * 256 + threadIdx.x;
    atomicAdd(&h[cid[i]], 1);
    __syncthreads();
    for (int c = threadIdx.x; c < Pn; c += 256)
        hist[blockIdx.x * Pn + c] = h[c];
}

// per-cluster total + per-chunk exclusive prefix (removes rank_kernel's chunk loop)
__global__ void counts_kernel(const int* __restrict__ hist, int* __restrict__ counts,
                              int* __restrict__ pref) {
    int c = blockIdx.x * 256 + threadIdx.x;
    int s = 0;
#pragma unroll
    for (int ch = 0; ch < 32; ++ch) {
        pref[ch * Pn + c] = s;
        s += hist[ch * Pn + c];
    }
    counts[c] = s;
}

__global__ void rank_kernel(const int* __restrict__ cid, const int* __restrict__ pref,
                            int* __restrict__ rank) {
    __shared__ int ids[256];
    int t = threadIdx.x;
    int i = blockIdx.x * 256 + t;
    ids[t] = cid[i];
    __syncthreads();
    int my = ids[t];
    int r = pref[blockIdx.x * Pn + my];
    for (int j = 0; j < t; ++j) r += (ids[j] == my) ? 1 : 0;
    rank[i] = r;
}

// exclusive scan of counts[4096] -> offs (one block, 256 threads x 16 each)
__global__ void offsets_kernel(const int* __restrict__ counts, int* __restrict__ offs) {
    __shared__ int wtot[4];
    int t = threadIdx.x;
    int local[16];
    int run = 0;
#pragma unroll
    for (int j = 0; j < 16; ++j) { local[j] = run; run += counts[t * 16 + j]; }
    int v = run;
#pragma unroll
    for (int d = 1; d < 64; d <<= 1) {
        int u = __shfl_up(v, d);
        if ((t & 63) >= d) v += u;
    }
    if ((t & 63) == 63) wtot[t >> 6] = v;
    __syncthreads();
    int add = 0;
    for (int ww = 0; ww < (t >> 6); ++ww) add += wtot[ww];
    int excl = add + v - run;
#pragma unroll
    for (int j = 0; j < 16; ++j) offs[t * 16 + j] = excl + local[j];
}

__global__ void fill_kernel(const int* __restrict__ cid, const int* __restrict__ rank,
                            const int* __restrict__ offs, int* __restrict__ slist) {
    int i = blockIdx.x * 256 + threadIdx.x;
    slist[offs[cid[i]] + rank[i]] = i;
}

// one wave per cluster: out[c] = M^cnt * p[c] + 0.1 * sum_j M^(cnt-1-j) * e_j  (no atomics)
__global__ void update_protos_kernel(const float* __restrict__ protos, const float* __restrict__ emb,
                                     const int* __restrict__ counts, const int* __restrict__ offs,
                                     const int* __restrict__ slist, float* __restrict__ outp) {
    int w = threadIdx.x >> 6, lane = threadIdx.x & 63;
    int c = blockIdx.x * 4 + w;
    int cnt = counts[c], off = offs[c];
    float4 p = reinterpret_cast<const float4*>(protos + (size_t)c * Dn)[lane];
    float scale = __powf(0.9f, (float)cnt);
    float4 acc;
    acc.x = p.x * scale; acc.y = p.y * scale; acc.z = p.z * scale; acc.w = p.w * scale;
    for (int j = 0; j < cnt; ++j) {
        int i = slist[off + j];
        float wgt = 0.1f * __powf(0.9f, (float)(cnt - 1 - j));
        float4 e = reinterpret_cast<const float4*>(emb + (size_t)i * Dn)[lane];
        acc.x += wgt * e.x; acc.y += wgt * e.y; acc.z += wgt * e.z; acc.w += wgt * e.w;
    }
    reinterpret_cast<float4*>(outp + (size_t)c * Dn)[lane] = acc;
}

extern "C" void kernel_launch(void* const* d_in, const int* in_sizes, int n_in,
                              void* d_out, int out_size, void* d_ws, size_t ws_size,
                              hipStream_t stream) {
    const float* emb    = (const float*)d_in[0];
    const float* protos = (const float*)d_in[1];
    const int*   cid    = (const int*)d_in[2];
    float* out = (float*)d_out;

    char* ws = (char*)d_ws;
    _Float16* embn = (_Float16*)ws;                                   // 4 MB
    _Float16* pron = (_Float16*)(ws + ((size_t)4 << 20));             // 2 MB
    float* s_glob  = (float*)(ws + ((size_t)6 << 20));                // 32 KB
    int*   counts  = (int*)(ws + ((size_t)6 << 20) + 32768);          // 16 KB
    int*   rank    = (int*)(ws + ((size_t)6 << 20) + 49152);          // 32 KB
    float* terms   = (float*)(ws + ((size_t)6 << 20) + 81920);        // 32 KB
    int*   offs    = (int*)(ws + ((size_t)6 << 20) + 114688);         // 16 KB
    int*   slist   = (int*)(ws + ((size_t)6 << 20) + 131072);         // 32 KB
    int*   hist    = (int*)(ws + ((size_t)7 << 20));                  // 512 KB
    int*   pref    = (int*)(ws + ((size_t)7 << 20) + 524288);         // 512 KB

    hipMemsetAsync(s_glob, 0, Bn * sizeof(float), stream);

    norm_rows_kernel<<<Bn / 4, 256, 0, stream>>>(emb, embn);
    norm_rows_kernel<<<Pn / 4, 256, 0, stream>>>(protos, pron);

    gemm_expsum_kernel<<<dim3(Bn / 128, Pn / 256), 256, 0, stream>>>(embn, pron, s_glob);
    loss_kernel<<<Bn / 4, 256, 0, stream>>>(embn, pron, cid, s_glob, terms);
    reduce_loss_kernel<<<1, 256, 0, stream>>>(terms, out);

    hist_kernel<<<Bn / 256, 256, 0, stream>>>(cid, hist);
    counts_kernel<<<Pn / 256, 256, 0, stream>>>(hist, counts, pref);
    rank_kernel<<<Bn / 256, 256, 0, stream>>>(cid, pref, rank);
    offsets_kernel<<<1, 256, 0, stream>>>(counts, offs);
    fill_kernel<<<Bn / 256, 256, 0, stream>>>(cid, rank, offs, slist);
    update_protos_kernel<<<Pn / 4, 256, 0, stream>>>(protos, emb, counts, offs, slist, out + 1);
}

// Round 4
// 129.015 us; speedup vs baseline: 2.1445x; 1.3163x over previous
//
#include <hip/hip_runtime.h>
#include <hip/hip_bf16.h>
#include <math.h>

#define Bn 8192
#define Dn 256
#define Pn 4096

using f16x8 = _Float16 __attribute__((ext_vector_type(8)));
using f16x4 = _Float16 __attribute__((ext_vector_type(4)));
using f32x16 = float __attribute__((ext_vector_type(16)));

// ------- normalize rows (fp32 -> f16), one wave per row; also zeros s_glob -------
// grid = (Bn+Pn)/4 blocks: rows [0,Bn) = embeddings, [Bn, Bn+Pn) = prototypes.
__global__ void norm_rows_kernel(const float* __restrict__ emb, const float* __restrict__ protos,
                                 _Float16* __restrict__ embn, _Float16* __restrict__ pron,
                                 float* __restrict__ s_glob) {
    int gid  = blockIdx.x;
    int row  = gid * 4 + (threadIdx.x >> 6);
    int lane = threadIdx.x & 63;
    const float* in;
    _Float16* out;
    int r;
    if (row < Bn) { in = emb;    out = embn; r = row; }
    else          { in = protos; out = pron; r = row - Bn; }
    const float4 v = reinterpret_cast<const float4*>(in + (size_t)r * Dn)[lane];
    float ss = v.x * v.x + v.y * v.y + v.z * v.z + v.w * v.w;
#pragma unroll
    for (int m = 1; m <= 32; m <<= 1) ss += __shfl_xor(ss, m);
    float scale = 1.0f / fmaxf(sqrtf(ss), 1e-12f);
    f16x4 o;
    o[0] = (_Float16)(v.x * scale);
    o[1] = (_Float16)(v.y * scale);
    o[2] = (_Float16)(v.z * scale);
    o[3] = (_Float16)(v.w * scale);
    reinterpret_cast<f16x4*>(out + (size_t)r * Dn)[lane] = o;
    if (gid < Bn / 1024) s_glob[gid * 256 + threadIdx.x] = 0.0f;  // zero 8192 floats
}

// ---------------- GEMM + exp-sum: s[row] += sum_p exp(sim-2) ----------------
// Block: 128 rows x 256 cols, 4 waves (32 rows each), A fully in registers.
// B staged in LDS FRAGMENT-MAJOR via global_load_lds (per-lane permuted global
// source, linear LDS dest, lane-linear reads -> zero bank conflicts).
// Double-buffered 32-col sub-chunks. grid = (64,16).
__global__ __launch_bounds__(256, 2)
void gemm_expsum_kernel(const _Float16* __restrict__ embn, const _Float16* __restrict__ pron,
                        float* __restrict__ s_glob) {
    __shared__ _Float16 Bs[2][32 * Dn];   // 2 x 16 KB
    const int w    = threadIdx.x >> 6;
    const int lane = threadIdx.x & 63;
    const int lo   = lane & 31;
    const int hi   = lane >> 5;
    const int rbase = blockIdx.x * 128 + w * 32;
    const int cbase = blockIdx.y * 256;

    // A fragments: lane lo -> row rbase+lo, elems k = kk*16 + hi*8 + j
    const _Float16* ap = embn + (size_t)(rbase + lo) * Dn + hi * 8;
    f16x8 a[16];
#pragma unroll
    for (int kk = 0; kk < 16; ++kk)
        a[kk] = *reinterpret_cast<const f16x8*>(ap + kk * 16);

    float s[16];
#pragma unroll
    for (int r = 0; r < 16; ++r) s[r] = 0.0f;

    constexpr float K1 = 2.0f * 1.4426950408889634f;  // (1/TEMP) * log2(e)

    // Fragment-major staging: granule g (=kk) -> LDS[g*1024 + lane*16] holds
    // exactly lane's B-frag slice for k-step g: pron[cbase+sub*32+lo][g*16+hi*8 ..+8]
    auto stage = [&](int sub, _Float16* buf) {
#pragma unroll
        for (int i = 0; i < 4; ++i) {
            int g = i * 4 + w;   // 16 granules per sub-chunk, 4 per wave
            const _Float16* gsrc =
                pron + (size_t)(cbase + sub * 32 + lo) * Dn + g * 16 + hi * 8;
            char* l = (char*)buf + (g << 10);   // wave-uniform base; +lane*16 implicit
            __builtin_amdgcn_global_load_lds(
                (const __attribute__((address_space(1))) unsigned int*)gsrc,
                (__attribute__((address_space(3))) unsigned int*)l, 16, 0, 0);
        }
    };

    stage(0, Bs[0]);
    __syncthreads();

    for (int sub = 0; sub < 8; ++sub) {
        const _Float16* cur = Bs[sub & 1];
        if (sub < 7) stage(sub + 1, Bs[(sub + 1) & 1]);   // async prefetch

        f32x16 acc;
#pragma unroll
        for (int r = 0; r < 16; ++r) acc[r] = 0.0f;
#pragma unroll
        for (int kk = 0; kk < 16; ++kk) {
            f16x8 b = *reinterpret_cast<const f16x8*>(
                (const char*)cur + (kk << 10) + (lane << 4));   // lane-linear
            acc = __builtin_amdgcn_mfma_f32_32x32x16_f16(a[kk], b, acc, 0, 0, 0);
        }
#pragma unroll
        for (int r = 0; r < 16; ++r)
            s[r] += exp2f(acc[r] * K1 - K1);

        __syncthreads();   // drains vmcnt (prefetch landed) + read-done before overwrite
    }

    // reduce across the 32 lanes holding the same row, then atomicAdd per row
#pragma unroll
    for (int r = 0; r < 16; ++r) {
        float v = s[r];
        v += __shfl_xor(v, 1);
        v += __shfl_xor(v, 2);
        v += __shfl_xor(v, 4);
        v += __shfl_xor(v, 8);
        v += __shfl_xor(v, 16);
        if (lo == 0) {
            int row = rbase + (r & 3) + 8 * (r >> 2) + 4 * hi;
            atomicAdd(&s_glob[row], v);
        }
    }
}

// ---------------- loss terms: per-row (lse - pos) ----------------
__global__ void loss_kernel(const _Float16* __restrict__ embn, const _Float16* __restrict__ pron,
                            const int* __restrict__ cid, const float* __restrict__ s_glob,
                            float* __restrict__ terms) {
    int row  = blockIdx.x * 4 + (threadIdx.x >> 6);
    int lane = threadIdx.x & 63;
    int c = cid[row];
    f16x4 e = reinterpret_cast<const f16x4*>(embn + (size_t)row * Dn)[lane];
    f16x4 p = reinterpret_cast<const f16x4*>(pron + (size_t)c * Dn)[lane];
    float d = 0.0f;
#pragma unroll
    for (int j = 0; j < 4; ++j) d += (float)e[j] * (float)p[j];
#pragma unroll
    for (int m = 1; m <= 32; m <<= 1) d += __shfl_xor(d, m);
    if (lane == 0) {
        float pos  = d * 2.0f;
        float sneg = s_glob[row] - __expf(pos - 2.0f);   // remove positive column
        float lse  = __logf(sneg) + 2.0f;
        terms[row] = lse - pos;
    }
}

// ---------------- single-block tree reduce of 8192 terms -> mean ----------------
__global__ void reduce_loss_kernel(const float* __restrict__ terms, float* __restrict__ loss) {
    int t = threadIdx.x;
    const float4* T = reinterpret_cast<const float4*>(terms);
    float s = 0.0f;
#pragma unroll
    for (int i = 0; i < Bn / 4 / 256; ++i) {
        float4 v = T[i * 256 + t];
        s += v.x + v.y + v.z + v.w;
    }
#pragma unroll
    for (int m = 1; m <= 32; m <<= 1) s += __shfl_xor(s, m);
    __shared__ float wsum[4];
    if ((t & 63) == 0) wsum[t >> 6] = s;
    __syncthreads();
    if (t == 0) loss[0] = (wsum[0] + wsum[1] + wsum[2] + wsum[3]) * (1.0f / (float)Bn);
}

// ---------------- EMA path: hist -> counts+prefix -> rank -> offsets -> CSR -> gather ----------------
__global__ void hist_kernel(const int* __restrict__ cid, int* __restrict__ hist) {
    __shared__ int h[Pn];
    for (int c = threadIdx.x; c < Pn; c += 256) h[c] = 0;
    __syncthreads();
    int i = blockIdx.x * 256 + threadIdx.x;
    atomicAdd(&h[cid[i]], 1);
    __syncthreads();
    for (int c = threadIdx.x; c < Pn; c += 256)
        hist[blockIdx.x * Pn + c] = h[c];
}

// per-cluster total + per-chunk exclusive prefix
__global__ void counts_kernel(const int* __restrict__ hist, int* __restrict__ counts,
                              int* __restrict__ pref) {
    int c = blockIdx.x * 256 + threadIdx.x;
    int s = 0;
#pragma unroll
    for (int ch = 0; ch < 32; ++ch) {
        pref[ch * Pn + c] = s;
        s += hist[ch * Pn + c];
    }
    counts[c] = s;
}

__global__ void rank_kernel(const int* __restrict__ cid, const int* __restrict__ pref,
                            int* __restrict__ rank) {
    __shared__ int ids[256];
    int t = threadIdx.x;
    int i = blockIdx.x * 256 + t;
    ids[t] = cid[i];
    __syncthreads();
    int my = ids[t];
    int r = pref[blockIdx.x * Pn + my];
    for (int j = 0; j < t; ++j) r += (ids[j] == my) ? 1 : 0;
    rank[i] = r;
}

// exclusive scan of counts[4096] -> offs (one block, 256 threads x 16 each)
__global__ void offsets_kernel(const int* __restrict__ counts, int* __restrict__ offs) {
    __shared__ int wtot[4];
    int t = threadIdx.x;
    int local[16];
    int run = 0;
#pragma unroll
    for (int j = 0; j < 16; ++j) { local[j] = run; run += counts[t * 16 + j]; }
    int v = run;
#pragma unroll
    for (int d = 1; d < 64; d <<= 1) {
        int u = __shfl_up(v, d);
        if ((t & 63) >= d) v += u;
    }
    if ((t & 63) == 63) wtot[t >> 6] = v;
    __syncthreads();
    int add = 0;
    for (int ww = 0; ww < (t >> 6); ++ww) add += wtot[ww];
    int excl = add + v - run;
#pragma unroll
    for (int j = 0; j < 16; ++j) offs[t * 16 + j] = excl + local[j];
}

__global__ void fill_kernel(const int* __restrict__ cid, const int* __restrict__ rank,
                            const int* __restrict__ offs, int* __restrict__ slist) {
    int i = blockIdx.x * 256 + threadIdx.x;
    slist[offs[cid[i]] + rank[i]] = i;
}

// one wave per cluster: out[c] = M^cnt * p[c] + 0.1 * sum_j M^(cnt-1-j) * e_j
__global__ void update_protos_kernel(const float* __restrict__ protos, const float* __restrict__ emb,
                                     const int* __restrict__ counts, const int* __restrict__ offs,
                                     const int* __restrict__ slist, float* __restrict__ outp) {
    int w = threadIdx.x >> 6, lane = threadIdx.x & 63;
    int c = blockIdx.x * 4 + w;
    int cnt = counts[c], off = offs[c];
    float4 p = reinterpret_cast<const float4*>(protos + (size_t)c * Dn)[lane];
    float scale = __powf(0.9f, (float)cnt);
    float4 acc;
    acc.x = p.x * scale; acc.y = p.y * scale; acc.z = p.z * scale; acc.w = p.w * scale;
    for (int j = 0; j < cnt; ++j) {
        int i = slist[off + j];
        float wgt = 0.1f * __powf(0.9f, (float)(cnt - 1 - j));
        float4 e = reinterpret_cast<const float4*>(emb + (size_t)i * Dn)[lane];
        acc.x += wgt * e.x; acc.y += wgt * e.y; acc.z += wgt * e.z; acc.w += wgt * e.w;
    }
    reinterpret_cast<float4*>(outp + (size_t)c * Dn)[lane] = acc;
}

extern "C" void kernel_launch(void* const* d_in, const int* in_sizes, int n_in,
                              void* d_out, int out_size, void* d_ws, size_t ws_size,
                              hipStream_t stream) {
    const float* emb    = (const float*)d_in[0];
    const float* protos = (const float*)d_in[1];
    const int*   cid    = (const int*)d_in[2];
    float* out = (float*)d_out;

    char* ws = (char*)d_ws;
    _Float16* embn = (_Float16*)ws;                                   // 4 MB
    _Float16* pron = (_Float16*)(ws + ((size_t)4 << 20));             // 2 MB
    float* s_glob  = (float*)(ws + ((size_t)6 << 20));                // 32 KB
    int*   counts  = (int*)(ws + ((size_t)6 << 20) + 32768);          // 16 KB
    int*   rank    = (int*)(ws + ((size_t)6 << 20) + 49152);          // 32 KB
    float* terms   = (float*)(ws + ((size_t)6 << 20) + 81920);        // 32 KB
    int*   offs    = (int*)(ws + ((size_t)6 << 20) + 114688);         // 16 KB
    int*   slist   = (int*)(ws + ((size_t)6 << 20) + 131072);         // 32 KB
    int*   hist    = (int*)(ws + ((size_t)7 << 20));                  // 512 KB
    int*   pref    = (int*)(ws + ((size_t)7 << 20) + 524288);         // 512 KB

    norm_rows_kernel<<<(Bn + Pn) / 4, 256, 0, stream>>>(emb, protos, embn, pron, s_glob);

    gemm_expsum_kernel<<<dim3(Bn / 128, Pn / 256), 256, 0, stream>>>(embn, pron, s_glob);
    loss_kernel<<<Bn / 4, 256, 0, stream>>>(embn, pron, cid, s_glob, terms);
    reduce_loss_kernel<<<1, 256, 0, stream>>>(terms, out);

    hist_kernel<<<Bn / 256, 256, 0, stream>>>(cid, hist);
    counts_kernel<<<Pn / 256, 256, 0, stream>>>(hist, counts, pref);
    rank_kernel<<<Bn / 256, 256, 0, stream>>>(cid, pref, rank);
    offsets_kernel<<<1, 256, 0, stream>>>(counts, offs);
    fill_kernel<<<Bn / 256, 256, 0, stream>>>(cid, rank, offs, slist);
    update_protos_kernel<<<Pn / 4, 256, 0, stream>>>(protos, emb, counts, offs, slist, out + 1);
}